// Round 10
// baseline (407.489 us; speedup 1.0000x reference)
//
#include <hip/hip_runtime.h>
#include <math.h>

using u16 = unsigned short;
using u32 = unsigned int;

typedef __attribute__((ext_vector_type(8))) short bf16x8;
typedef __attribute__((ext_vector_type(4))) float f32x4;

#define B_   4
#define S_   2048
#define D_   512
#define H_   8
#define HD_  64
#define N_   1024
#define E_   16384
#define DFF_ 2048
#define BS_  (B_ * S_)   // 8192 token rows
#define BN_  (B_ * N_)   // 4096 node rows
#define QSCALE 0.18033688011112042f   // 0.125 * log2(e): scores in log2 domain
#define KSTRIDE 68                    // 34 words ≡ 2 (mod 32) -> conflict-free col stride
#define KSPLIT 2                      // measured best (4-way worse; direct-global worse)

// ---------- bf16 helpers ----------
__device__ __forceinline__ float bf2f(u16 u) {
  u32 v = (u32)u << 16; float f; __builtin_memcpy(&f, &v, 4); return f;
}
__device__ __forceinline__ u16 f2bf(float f) {
  u32 u; __builtin_memcpy(&u, &f, 4);
  u = u + 0x7fffu + ((u >> 16) & 1u);
  return (u16)(u >> 16);
}
__device__ __forceinline__ float bflo(u32 w) {
  u32 v = w << 16; float f; __builtin_memcpy(&f, &v, 4); return f;
}
__device__ __forceinline__ float bfhi(u32 w) {
  u32 v = w & 0xffff0000u; float f; __builtin_memcpy(&f, &v, 4); return f;
}
__device__ __forceinline__ u32 fbits(float f) { u32 u; __builtin_memcpy(&u, &f, 4); return u; }

// ---------- batched weight transpose + f32->bf16 ----------
__global__ __launch_bounds__(256) void tpose_all(const float* __restrict__ Wq, const float* __restrict__ Wk,
                                                 const float* __restrict__ Wv, const float* __restrict__ Wo,
                                                 const float* __restrict__ Wgs, const float* __restrict__ Wgn,
                                                 const float* __restrict__ Wg, const float* __restrict__ Wf1,
                                                 const float* __restrict__ Wf2, u16* __restrict__ wsbase) {
  __shared__ u16 t[32][33];
  const int z = blockIdx.z;
  const float* src; int C, r0, c0, ds, co; long doff;
  const long SL = 262144;   // 512*512 u16 slot
  switch (z) {
    case 0:  src = Wq;  C = 512;  r0 = 0;   c0 = 0;    ds = 512;  co = 0;   doff = 0;       break;
    case 1:  src = Wk;  C = 512;  r0 = 0;   c0 = 0;    ds = 512;  co = 0;   doff = 1 * SL;  break;
    case 2:  src = Wv;  C = 512;  r0 = 0;   c0 = 0;    ds = 512;  co = 0;   doff = 2 * SL;  break;
    case 3:  src = Wo;  C = 512;  r0 = 0;   c0 = 0;    ds = 512;  co = 0;   doff = 3 * SL;  break;
    case 4:  src = Wg;  C = 512;  r0 = 0;   c0 = 0;    ds = 1024; co = 0;   doff = 4 * SL;  break;
    case 5:  src = Wg;  C = 512;  r0 = 512; c0 = 0;    ds = 1024; co = 512; doff = 4 * SL;  break;
    case 6:  src = Wgs; C = 512;  r0 = 0;   c0 = 0;    ds = 1024; co = 0;   doff = 6 * SL;  break;
    case 7:  src = Wgn; C = 512;  r0 = 0;   c0 = 0;    ds = 1024; co = 512; doff = 6 * SL;  break;
    case 8: case 9: case 10: case 11:
             src = Wf1; C = 2048; r0 = 0;   c0 = (z - 8) * 512;  ds = 512;  co = 0; doff = 8 * SL;  break;
    default: src = Wf2; C = 512;  r0 = (z - 12) * 512; c0 = 0;   ds = 2048; co = (z - 12) * 512; doff = 12 * SL; break;
  }
  u16* dst = wsbase + doff;
  int rb = blockIdx.x * 32, cb = blockIdx.y * 32 + c0;
  int tx = threadIdx.x, ty = threadIdx.y;
  #pragma unroll
  for (int i = ty; i < 32; i += 8) t[i][tx] = f2bf(src[(long)(r0 + rb + i) * C + cb + tx]);
  __syncthreads();
  #pragma unroll
  for (int i = ty; i < 32; i += 8) dst[(long)(cb + i) * ds + co + rb + tx] = t[tx][i];
}

// ---------- pack q/k/v biases ----------
__global__ void packb_k(const float* __restrict__ bq, const float* __restrict__ bk,
                        const float* __restrict__ bv, float* __restrict__ o) {
  int i = blockIdx.x * 256 + threadIdx.x;
  if (i < 512) o[i] = bq[i];
  else if (i < 1024) o[i] = bk[i - 512];
  else if (i < 1536) o[i] = bv[i - 1024];
}

// ---------- LayerNorm over D=512 (f32 in, bf16 out) ----------
__global__ __launch_bounds__(256) void ln_k(const float* __restrict__ x, const float* __restrict__ g,
                                            const float* __restrict__ be, u16* __restrict__ out) {
  __shared__ float red[8];
  long row = blockIdx.x;
  int t = threadIdx.x;
  const float* xr = x + row * D_;
  float2 v = *(const float2*)(xr + 2 * t);
  float s = v.x + v.y, sq = v.x * v.x + v.y * v.y;
  #pragma unroll
  for (int m = 32; m >= 1; m >>= 1) { s += __shfl_xor(s, m, 64); sq += __shfl_xor(sq, m, 64); }
  if ((t & 63) == 0) { red[t >> 6] = s; red[4 + (t >> 6)] = sq; }
  __syncthreads();
  s = red[0] + red[1] + red[2] + red[3];
  sq = red[4] + red[5] + red[6] + red[7];
  float mean = s * (1.f / D_);
  float var = sq * (1.f / D_) - mean * mean;
  float rs = rsqrtf(fmaxf(var, 0.f) + 1e-5f);
  float2 gw = *(const float2*)(g + 2 * t);
  float2 bw = *(const float2*)(be + 2 * t);
  u32 o = (u32)f2bf((v.x - mean) * rs * gw.x + bw.x) | ((u32)f2bf((v.y - mean) * rs * gw.y + bw.y) << 16);
  *(u32*)&out[row * D_ + 2 * t] = o;
}

// ---------- MFMA GEMM: 3-deep ring + counted vmcnt (T3/T4) + XOR bank-swizzle (T2) ----------
// r9 profile: FFN1 was the largest dispatch (81us, MfmaUtil 8%); SQ_LDS_BANK_CONFLICT
// saturated at 2^21 — the 64B-row-stride LDS tile is an 8-way conflict on ds_read_b128.
// Fix per rule #21 (both-sides-or-neither with global_load_lds): linear LDS dest,
// inverse-swizzled GLOBAL source (chunk (tid&3)^((tid>>3)&3)), swizzled read
// (kchunk = (lane>>4)^((rsel>>1)&3), a per-thread CONSTANT). 8-way -> 2-way (free, m136).
// Schedule: 3-buffer ring; per 32-K iter: s_waitcnt vmcnt(L) (counted, NOT 0) + ONE raw
// s_barrier + ds_read/MFMA + stage(t+2). Loads span ~1.5 iters; drain-to-0 only at tail.
__device__ __forceinline__ void async_cp16(const u16* g, u16* l) {
  __builtin_amdgcn_global_load_lds((const __attribute__((address_space(1))) void*)g,
                                   (__attribute__((address_space(3))) void*)l, 16, 0, 0);
}

enum { EPI_QKV3, EPI_XF32, EPI_BF, EPI_RELU_SCATTER, EPI_GELU };

template <int EPI, bool CAT = false, int TM = 128>
__global__ __launch_bounds__(256) void gemm_k(const u16* __restrict__ A, const u16* __restrict__ A2,
                                              const u16* __restrict__ Bt, const float* __restrict__ bias,
                                              const void* src, void* out, const int* __restrict__ rowmap,
                                              int M, int N, int K) {
  constexpr int MT = TM / 32;              // m-subtiles per wave (TM=32 -> 1)
  __shared__ __align__(16) u16 As[3][TM * 32];
  __shared__ __align__(16) u16 Bs[3][4096];   // 128 x 32 each
  int tid = threadIdx.x;
  int lane = tid & 63;
  int wn = (tid >> 6) & 1;
  int wm = (tid >> 7) & 1;
  // T1 XCD swizzle (all launches have nwg % 8 == 0)
  int nwg = gridDim.x * gridDim.y;
  int orig = blockIdx.y * gridDim.x + blockIdx.x;
  int wgid = ((orig & 7) * (nwg >> 3)) + (orig >> 3);
  int bx = wgid % gridDim.x;
  int by = wgid / gridDim.x;
  long m0 = (long)by * TM;
  long n0 = (long)bx * 128;

  f32x4 acc[MT][4];
  {
    f32x4 z = {0.f, 0.f, 0.f, 0.f};
    #pragma unroll
    for (int i = 0; i < MT; i++)
      #pragma unroll
      for (int j = 0; j < 4; j++) acc[i][j] = z;
  }

  const int astride = CAT ? 512 : K;
  // A-source thread id: TM==32 stages A with tid&127 (waves 2-3 duplicate identical
  // data -> uniform vmcnt count L across waves; benign same-value LDS stores).
  int ta = (TM == 32) ? (tid & 127) : tid;
  int srowA = ta >> 2;
  int skA = (((ta & 3) ^ ((ta >> 3) & 3)) * 8);     // T2 inverse-swizzled source chunk
  int srowB = tid >> 2;
  int skB = (((tid & 3) ^ ((tid >> 3) & 3)) * 8);
  const u16* AgA  = A + (m0 + srowA) * (long)astride + skA;
  const u16* A2gA = CAT ? (A2 + (m0 + srowA) * (long)astride + skA) : nullptr;
  const u16* BgB  = Bt + (n0 + srowB) * (long)K + skB;
  int rsel = lane & 15;
  int kchunk = (((lane >> 4) ^ ((rsel >> 1) & 3)) * 8);   // T2 read swizzle (constant)

  auto stage = [&](int buf, int kts) {
    const u16* Asrc = (CAT && kts >= 512) ? (A2gA + (kts - 512)) : (AgA + kts);
    if constexpr (TM == 32) {
      async_cp16(Asrc, &As[buf][ta * 8]);
    } else {
      async_cp16(Asrc, &As[buf][tid * 8]);
      async_cp16(Asrc + (long)64 * astride, &As[buf][2048 + tid * 8]);
    }
    async_cp16(BgB + kts, &Bs[buf][tid * 8]);
    async_cp16(BgB + (long)64 * K + kts, &Bs[buf][2048 + tid * 8]);
  };
  // stage insts per wave: TM==128: 2A+2B=4; TM==32: 1A(dup)+2B=3

  const int T = K / 32;
  stage(0, 0);
  stage(1, 32);
  int b = 0;
  for (int t = 0; t < T; ++t) {
    if (t == T - 1) {
      asm volatile("s_waitcnt vmcnt(0)" ::: "memory");
    } else {
      if constexpr (TM == 128) asm volatile("s_waitcnt vmcnt(4)" ::: "memory");
      else                     asm volatile("s_waitcnt vmcnt(3)" ::: "memory");
    }
    __builtin_amdgcn_s_barrier();   // S(t) visible everywhere; prior-iter readers done
    bf16x8 af[MT], bfv[4];
    #pragma unroll
    for (int mt = 0; mt < MT; mt++)
      af[mt] = *(const bf16x8*)&As[b][(wm * (TM / 2) + mt * 16 + rsel) * 32 + kchunk];
    #pragma unroll
    for (int nt = 0; nt < 4; nt++)
      bfv[nt] = *(const bf16x8*)&Bs[b][(wn * 64 + nt * 16 + rsel) * 32 + kchunk];
    #pragma unroll
    for (int mt = 0; mt < MT; mt++)
      #pragma unroll
      for (int nt = 0; nt < 4; nt++)
        acc[mt][nt] = __builtin_amdgcn_mfma_f32_16x16x32_bf16(af[mt], bfv[nt], acc[mt][nt], 0, 0, 0);
    if (t + 2 < T) stage((t + 2) % 3, (t + 2) * 32);   // overwrites buf (t-1)%3: safe past this iter's barrier
    if (++b == 3) b = 0;
  }

  int rbase = (lane >> 4) * 4;   // C layout: row = quad*4 + reg, col = lane&15 (m89-verified)
  int cbase = lane & 15;
  #pragma unroll
  for (int mt = 0; mt < MT; mt++) {
    #pragma unroll
    for (int nt = 0; nt < 4; nt++) {
      long col = n0 + wn * 64 + nt * 16 + cbase;
      float bv = bias ? bias[col] : 0.f;
      long row0 = m0 + wm * (TM / 2) + mt * 16 + rbase;
      float vals[4];
      #pragma unroll
      for (int r = 0; r < 4; r++) vals[r] = acc[mt][nt][r] + bv;
      if constexpr (EPI == EPI_QKV3) {
        long which = col >> 9;            // 0=q, 1=k, 2=v
        long cc = col & 511;
        long b2 = row0 >> 11;
        long h = cc >> 6, d = cc & 63;
        if (which == 2) {                 // V transposed [b,h,d,key]; 4 consecutive keys
          long sI0 = row0 & 2047;
          uint2 w;
          w.x = (u32)f2bf(vals[0]) | ((u32)f2bf(vals[1]) << 16);
          w.y = (u32)f2bf(vals[2]) | ((u32)f2bf(vals[3]) << 16);
          *(uint2*)&((u16*)out)[2 * (long)BS_ * D_ + (((b2 * H_ + h) * HD_) + d) * S_ + sI0] = w;
        } else {
          #pragma unroll
          for (int r = 0; r < 4; r++) {
            long sI = (row0 + r) & 2047;
            float v2 = (which == 0) ? vals[r] * QSCALE : vals[r];
            ((u16*)out)[which * (long)BS_ * D_ + (((b2 * H_ + h) * S_) + sI) * HD_ + d] = f2bf(v2);
          }
        }
      } else {
        #pragma unroll
        for (int r = 0; r < 4; r++) {
          long row = row0 + r;
          float val = vals[r];
          if constexpr (EPI == EPI_XF32) {
            ((float*)out)[row * N + col] = val + ((const float*)src)[row * N + col];
          } else if constexpr (EPI == EPI_BF) {
            ((u16*)out)[row * N + col] = f2bf(val);
          } else if constexpr (EPI == EPI_RELU_SCATTER) {
            long orow = rowmap[row];
            ((u16*)out)[orow * D_ + col] = f2bf(fmaxf(val, 0.f));
          } else if constexpr (EPI == EPI_GELU) {
            ((u16*)out)[row * N + col] = f2bf(0.5f * val * (1.f + erff(val * 0.70710678118654752f)));
          }
        }
      }
    }
  }
}

// ---------- MFMA flash attention, S^T scheme, 2 q-tiles/wave, 2-way K-split ----------
// MEASURED OPTIMUM — byte-identical to r6/r9. Single-buffered LDS, NO setprio, NO
// prefetch: sits exactly on the 64-VGPR wave-residency cliff (m69); r7 (prefetch,
// VGPR 76) and r8 (setprio, VGPR 68) both crossed it -> occupancy 32->21, +10us.
__global__ __launch_bounds__(256) void attn_k(const u16* __restrict__ Q, const u16* __restrict__ Kv,
                                              const u16* __restrict__ VT, u16* __restrict__ Opart,
                                              float* __restrict__ Lp) {
  __shared__ __align__(16) u16 Ks[64 * KSTRIDE];
  __shared__ __align__(16) u16 Vs[64 * KSTRIDE];
  int tid = threadIdx.x;
  int lane = tid & 63;
  int wave = tid >> 6;
  int col = lane & 15;
  int quad = lane >> 4;
  int bh = blockIdx.y;
  int q0 = blockIdx.x * 128;
  int khalf = blockIdx.z;
  long base = (long)bh * S_;
  long vbase = (long)bh * HD_ * S_;

  const u16* qpa = Q + (base + q0 + wave * 32 + col) * HD_;
  const u16* qpb = qpa + 16 * HD_;
  bf16x8 bqa0 = *(const bf16x8*)(qpa + quad * 8);
  bf16x8 bqa1 = *(const bf16x8*)(qpa + 32 + quad * 8);
  bf16x8 bqb0 = *(const bf16x8*)(qpb + quad * 8);
  bf16x8 bqb1 = *(const bf16x8*)(qpb + 32 + quad * 8);

  float la = 0.f, lb = 0.f;
  f32x4 accA[4], accB[4];
  {
    f32x4 z = {0.f, 0.f, 0.f, 0.f};
    #pragma unroll
    for (int mt = 0; mt < 4; mt++) { accA[mt] = z; accB[mt] = z; }
  }

  int srow = tid >> 2;
  int sdc = (tid & 3) * 16;
  const bool hiQ = (quad >= 2);
  const int s0 = (quad & 1) * 2;
  const int a0 = (s0 * 16 + col + wave * 64) * 4;
  const int a1 = ((s0 + 1) * 16 + col + wave * 64) * 4;

  int kt0 = khalf * (S_ / KSPLIT);
  for (int kt = kt0; kt < kt0 + S_ / KSPLIT; kt += 64) {
    __syncthreads();
    {
      const u16* kg = Kv + (base + kt + srow) * HD_ + sdc;
      *(bf16x8*)&Ks[srow * KSTRIDE + sdc]     = *(const bf16x8*)kg;
      *(bf16x8*)&Ks[srow * KSTRIDE + sdc + 8] = *(const bf16x8*)(kg + 8);
      const u16* vg = VT + (vbase + (long)srow * S_) + kt + sdc;
      *(bf16x8*)&Vs[srow * KSTRIDE + sdc]     = *(const bf16x8*)vg;
      *(bf16x8*)&Vs[srow * KSTRIDE + sdc + 8] = *(const bf16x8*)(vg + 8);
    }
    __syncthreads();

    f32x4 sa[4], sb[4];
    #pragma unroll
    for (int nt = 0; nt < 4; nt++) {
      bf16x8 ak0 = *(const bf16x8*)&Ks[(nt * 16 + col) * KSTRIDE + quad * 8];
      bf16x8 ak1 = *(const bf16x8*)&Ks[(nt * 16 + col) * KSTRIDE + 32 + quad * 8];
      f32x4 z = {0.f, 0.f, 0.f, 0.f};
      z = __builtin_amdgcn_mfma_f32_16x16x32_bf16(ak0, bqa0, z, 0, 0, 0);
      z = __builtin_amdgcn_mfma_f32_16x16x32_bf16(ak1, bqa1, z, 0, 0, 0);
      sa[nt] = z;
      f32x4 y = {0.f, 0.f, 0.f, 0.f};
      y = __builtin_amdgcn_mfma_f32_16x16x32_bf16(ak0, bqb0, y, 0, 0, 0);
      y = __builtin_amdgcn_mfma_f32_16x16x32_bf16(ak1, bqb1, y, 0, 0, 0);
      sb[nt] = y;
    }

    u32 pka[4][2], pkb[4][2];
    #pragma unroll
    for (int nt = 0; nt < 4; nt++) {
      #pragma unroll
      for (int r = 0; r < 4; r++) { sa[nt][r] = __builtin_amdgcn_exp2f(sa[nt][r]); sb[nt][r] = __builtin_amdgcn_exp2f(sb[nt][r]); }
      la += (sa[nt][0] + sa[nt][1]) + (sa[nt][2] + sa[nt][3]);
      lb += (sb[nt][0] + sb[nt][1]) + (sb[nt][2] + sb[nt][3]);
      pka[nt][0] = __builtin_amdgcn_perm(fbits(sa[nt][1]), fbits(sa[nt][0]), 0x07060302u);
      pka[nt][1] = __builtin_amdgcn_perm(fbits(sa[nt][3]), fbits(sa[nt][2]), 0x07060302u);
      pkb[nt][0] = __builtin_amdgcn_perm(fbits(sb[nt][1]), fbits(sb[nt][0]), 0x07060302u);
      pkb[nt][1] = __builtin_amdgcn_perm(fbits(sb[nt][3]), fbits(sb[nt][2]), 0x07060302u);
    }

    union { u32 d[4]; bf16x8 v; } ba0, ba1, bb0, bb1;
    {
      u32 sA = hiQ ? pka[1][0] : pka[0][0];
      u32 sB = hiQ ? pka[1][1] : pka[0][1];
      ba0.d[0] = __builtin_amdgcn_ds_bpermute(a0, sA);
      ba0.d[1] = __builtin_amdgcn_ds_bpermute(a0, sB);
      ba0.d[2] = __builtin_amdgcn_ds_bpermute(a1, sA);
      ba0.d[3] = __builtin_amdgcn_ds_bpermute(a1, sB);
      u32 sC = hiQ ? pka[3][0] : pka[2][0];
      u32 sD = hiQ ? pka[3][1] : pka[2][1];
      ba1.d[0] = __builtin_amdgcn_ds_bpermute(a0, sC);
      ba1.d[1] = __builtin_amdgcn_ds_bpermute(a0, sD);
      ba1.d[2] = __builtin_amdgcn_ds_bpermute(a1, sC);
      ba1.d[3] = __builtin_amdgcn_ds_bpermute(a1, sD);
      u32 tA = hiQ ? pkb[1][0] : pkb[0][0];
      u32 tB = hiQ ? pkb[1][1] : pkb[0][1];
      bb0.d[0] = __builtin_amdgcn_ds_bpermute(a0, tA);
      bb0.d[1] = __builtin_amdgcn_ds_bpermute(a0, tB);
      bb0.d[2] = __builtin_amdgcn_ds_bpermute(a1, tA);
      bb0.d[3] = __builtin_amdgcn_ds_bpermute(a1, tB);
      u32 tC = hiQ ? pkb[3][0] : pkb[2][0];
      u32 tD = hiQ ? pkb[3][1] : pkb[2][1];
      bb1.d[0] = __builtin_amdgcn_ds_bpermute(a0, tC);
      bb1.d[1] = __builtin_amdgcn_ds_bpermute(a0, tD);
      bb1.d[2] = __builtin_amdgcn_ds_bpermute(a1, tC);
      bb1.d[3] = __builtin_amdgcn_ds_bpermute(a1, tD);
    }

    #pragma unroll
    for (int mt = 0; mt < 4; mt++) {
      bf16x8 av0 = *(const bf16x8*)&Vs[(mt * 16 + col) * KSTRIDE + quad * 8];
      bf16x8 av1 = *(const bf16x8*)&Vs[(mt * 16 + col) * KSTRIDE + 32 + quad * 8];
      accA[mt] = __builtin_amdgcn_mfma_f32_16x16x32_bf16(av0, ba0.v, accA[mt], 0, 0, 0);
      accA[mt] = __builtin_amdgcn_mfma_f32_16x16x32_bf16(av1, ba1.v, accA[mt], 0, 0, 0);
      accB[mt] = __builtin_amdgcn_mfma_f32_16x16x32_bf16(av0, bb0.v, accB[mt], 0, 0, 0);
      accB[mt] = __builtin_amdgcn_mfma_f32_16x16x32_bf16(av1, bb1.v, accB[mt], 0, 0, 0);
    }
  }

  la += __shfl_xor(la, 16, 64);
  la += __shfl_xor(la, 32, 64);
  lb += __shfl_xor(lb, 16, 64);
  lb += __shfl_xor(lb, 32, 64);

  int b = bh >> 3, h = bh & 7;
  long qrowA = (long)(b * S_) + q0 + wave * 32 + col;
  u16* Pp = Opart + (long)khalf * BS_ * D_;
  if (quad == 0) {
    float* lr = Lp + ((long)(khalf * 32 + bh)) * S_ + q0 + wave * 32;
    lr[col] = la;
    lr[16 + col] = lb;
  }
  u16* opA = Pp + qrowA * D_ + h * HD_ + quad * 4;
  u16* opB = Pp + (qrowA + 16) * D_ + h * HD_ + quad * 4;
  #pragma unroll
  for (int mt = 0; mt < 4; mt++) {
    uint2 w;
    w.x = (u32)f2bf(accA[mt][0]) | ((u32)f2bf(accA[mt][1]) << 16);
    w.y = (u32)f2bf(accA[mt][2]) | ((u32)f2bf(accA[mt][3]) << 16);
    *(uint2*)(opA + mt * 16) = w;
    uint2 v;
    v.x = (u32)f2bf(accB[mt][0]) | ((u32)f2bf(accB[mt][1]) << 16);
    v.y = (u32)f2bf(accB[mt][2]) | ((u32)f2bf(accB[mt][3]) << 16);
    *(uint2*)(opB + mt * 16) = v;
  }
}

// ---------- combine K-split partials: ao = sum(Pk) / sum(lk) ----------
__global__ __launch_bounds__(256) void acomb_k(const u16* __restrict__ P, const float* __restrict__ Lp,
                                               u16* __restrict__ AO) {
  long i = (long)blockIdx.x * 256 + threadIdx.x;   // uint2 = 4 bf16 elems
  long e0 = i * 4;
  long tok = e0 >> 9;             // /512
  int hh = (int)((e0 >> 6) & 7);
  long s = tok & 2047;
  long bb = tok >> 11;
  long bh = bb * 8 + hh;
  float l = 0.f;
  float v0 = 0.f, v1 = 0.f, v2 = 0.f, v3 = 0.f;
  #pragma unroll
  for (int k = 0; k < KSPLIT; k++) {
    uint2 a = ((const uint2*)(P + (long)k * BS_ * D_))[i];
    v0 += bflo(a.x); v1 += bfhi(a.x);
    v2 += bflo(a.y); v3 += bfhi(a.y);
    l += Lp[((long)(k * 32) + bh) * S_ + s];
  }
  float inv = 1.f / l;
  uint2 o;
  o.x = (u32)f2bf(v0 * inv) | ((u32)f2bf(v1 * inv) << 16);
  o.y = (u32)f2bf(v2 * inv) | ((u32)f2bf(v3 * inv) << 16);
  ((uint2*)AO)[i] = o;
}

// ---------- GNN plumbing ----------
// gather nx2 node rows into Acat cols 0..511; also emits rowmap for the scatter epilogue
__global__ __launch_bounds__(128) void gather_k(const u16* __restrict__ nx2, const int* __restrict__ nidx,
                                                int* __restrict__ rowmap, u16* __restrict__ Acat) {
  int bn = blockIdx.x;
  int t = threadIdx.x;
  long srow = (long)(bn >> 10) * S_ + nidx[bn];
  if (t == 0) rowmap[bn] = (int)srow;
  const u32* sp = (const u32*)(nx2 + srow * D_);
  u32* dp = (u32*)(Acat + (long)bn * 1024);
  dp[t] = sp[t];
  dp[t + 128] = sp[t + 128];
}

// ---------- atomic-free segment sum: one block per dst node ----------
#define DEG_CAP 256
__global__ __launch_bounds__(256) void agg_k(const int* __restrict__ ei, u16* __restrict__ Acat) {
  __shared__ int cnt;
  __shared__ int lst[DEG_CAP];
  int n = blockIdx.x;
  int t = threadIdx.x;
  if (t == 0) cnt = 0;
  __syncthreads();
  const int* dst = ei + E_;
  for (int e = t; e < E_; e += 256) {
    if (dst[e] == n) {
      int idx = atomicAdd(&cnt, 1);
      if (idx < DEG_CAP) lst[idx] = ei[e];
    }
  }
  __syncthreads();
  int mcnt = cnt < DEG_CAP ? cnt : DEG_CAP;
  float2 acc[4] = {{0.f, 0.f}, {0.f, 0.f}, {0.f, 0.f}, {0.f, 0.f}};
  for (int i = 0; i < mcnt; i++) {
    long s = lst[i];
    #pragma unroll
    for (int b = 0; b < 4; b++) {
      u32 w = *(const u32*)&Acat[((long)(b * N_) + s) * 1024 + 2 * t];
      acc[b].x += bflo(w);
      acc[b].y += bfhi(w);
    }
  }
  #pragma unroll
  for (int b = 0; b < 4; b++) {
    u32 r = (u32)f2bf(acc[b].x) | ((u32)f2bf(acc[b].y) << 16);
    *(u32*)&Acat[((long)(b * N_) + n) * 1024 + 512 + 2 * t] = r;
  }
}

// ---------- fused gated combine + LN3 ----------
__global__ __launch_bounds__(256) void combln_k(const float* __restrict__ x1, const u16* __restrict__ gpre,
                                                const u16* __restrict__ gnn, const u16* __restrict__ nx2,
                                                const float* __restrict__ g3, const float* __restrict__ be3,
                                                float* __restrict__ x2, u16* __restrict__ nx3) {
  __shared__ float red[8];
  long row = blockIdx.x;
  int t = threadIdx.x;
  long off = row * D_ + 2 * t;
  float2 a = *(const float2*)(x1 + off);
  u32 gp = *(const u32*)(gpre + off);
  u32 gn = *(const u32*)(gnn + off);
  u32 nv = *(const u32*)(nx2 + off);
  float g0 = 1.f / (1.f + __expf(-bflo(gp)));
  float g1 = 1.f / (1.f + __expf(-bfhi(gp)));
  float t0 = a.x + g0 * bflo(gn) + (1.f - g0) * bflo(nv);
  float t1 = a.y + g1 * bfhi(gn) + (1.f - g1) * bfhi(nv);
  float2 w = {t0, t1};
  *(float2*)(x2 + off) = w;
  float s = t0 + t1, sq = t0 * t0 + t1 * t1;
  #pragma unroll
  for (int m = 32; m >= 1; m >>= 1) { s += __shfl_xor(s, m, 64); sq += __shfl_xor(sq, m, 64); }
  if ((t & 63) == 0) { red[t >> 6] = s; red[4 + (t >> 6)] = sq; }
  __syncthreads();
  s = red[0] + red[1] + red[2] + red[3];
  sq = red[4] + red[5] + red[6] + red[7];
  float mean = s * (1.f / D_);
  float var = sq * (1.f / D_) - mean * mean;
  float rs = rsqrtf(fmaxf(var, 0.f) + 1e-5f);
  float2 gw = *(const float2*)(g3 + 2 * t);
  float2 bw = *(const float2*)(be3 + 2 * t);
  u32 o = (u32)f2bf((t0 - mean) * rs * gw.x + bw.x) | ((u32)f2bf((t1 - mean) * rs * gw.y + bw.y) << 16);
  *(u32*)&nx3[off] = o;
}

// ---------- orchestration ----------
extern "C" void kernel_launch(void* const* d_in, const int* in_sizes, int n_in,
                              void* d_out, int out_size, void* d_ws, size_t ws_size,
                              hipStream_t stream) {
  const float* x  = (const float*)d_in[0];
  const int* ei   = (const int*)d_in[1];
  const int* nidx = (const int*)d_in[2];
  const float* Wq = (const float*)d_in[3];   const float* bq = (const float*)d_in[4];
  const float* Wk = (const float*)d_in[5];   const float* bk = (const float*)d_in[6];
  const float* Wv = (const float*)d_in[7];   const float* bv = (const float*)d_in[8];
  const float* Wo = (const float*)d_in[9];   const float* bo = (const float*)d_in[10];
  const float* Wf1 = (const float*)d_in[11]; const float* bf1 = (const float*)d_in[12];
  const float* Wf2 = (const float*)d_in[13]; const float* bf2v = (const float*)d_in[14];
  const float* g1 = (const float*)d_in[15];  const float* be1 = (const float*)d_in[16];
  const float* g2 = (const float*)d_in[17];  const float* be2 = (const float*)d_in[18];
  const float* g3 = (const float*)d_in[19];  const float* be3 = (const float*)d_in[20];
  const float* Wg = (const float*)d_in[21];  const float* bg = (const float*)d_in[22];
  const float* Wgs = (const float*)d_in[23]; const float* Wgn = (const float*)d_in[24];
  const float* bgn = (const float*)d_in[25];

  const size_t MB8 = (size_t)8 * 1024 * 1024;
  char* base = (char*)d_ws;
  const size_t SLOT = (size_t)512 * 512 * 2;   // 512 KB
  u16* WqT     = (u16*)(base + 0 * SLOT);
  u16* WoT     = (u16*)(base + 3 * SLOT);
  u16* WgFullT = (u16*)(base + 4 * SLOT);
  u16* WgsgnT  = (u16*)(base + 6 * SLOT);
  u16* Wf1T    = (u16*)(base + 8 * SLOT);
  u16* Wf2T    = (u16*)(base + 12 * SLOT);

  char* RA   = base + 16 * SLOT;   // 8M: nx -> ao -> gnn -> nx3
  char* Rqb  = RA + MB8;           // 8M
  char* Rkb  = Rqb + MB8;          // 8M
  char* Rvb  = Rkb + MB8;          // 8M
  char* Rac  = Rvb + MB8;          // 8M: Opart[0] -> Acat -> gpre
  char* Rag  = Rac + MB8;          // 8M: Opart[1]
  char* Rx2  = Rag + MB8;          // 16M: x2 (f32)
  char* RM   = Rx2 + 2 * MB8;      // rowmap 16KB + qkvb 6KB + Lpart 512KB

  u16* nx   = (u16*)RA;   u16* ao  = (u16*)RA;   u16* gnn = (u16*)RA;  u16* nx3 = (u16*)RA;
  u16* qb   = (u16*)Rqb;           // q | k | v^T contiguous (EPI_QKV3 offsets)
  float* x1 = (float*)Rqb;
  u16* nx2  = (u16*)Rvb;
  u16* Opart = (u16*)Rac;          // KSPLIT x 8MB contiguous (Rac,Rag); dead before Acat/gpre
  u16* Acat = (u16*)Rac;
  u16* gpre = (u16*)Rac;
  float* x2 = (float*)Rx2;
  u16* ffh  = (u16*)Rqb;
  int* rowmap = (int*)RM;
  float* qkvb = (float*)(RM + 16384);
  float* Lpart = (float*)(RM + 32768);   // KSPLIT*32*2048 f32 = 512KB

  dim3 tb(32, 8);
  tpose_all<<<dim3(16, 16, 16), tb, 0, stream>>>(Wq, Wk, Wv, Wo, Wgs, Wgn, Wg, Wf1, Wf2, (u16*)base);
  packb_k<<<6, 256, 0, stream>>>(bq, bk, bv, qkvb);

  // LN1 -> fused QKV (Q scaled, V transposed) -> K-split attention -> combine -> O-proj (+x residual)
  ln_k<<<BS_, 256, 0, stream>>>(x, g1, be1, nx);
  gemm_k<EPI_QKV3, false, 128><<<dim3(12, 64), 256, 0, stream>>>(nx, nullptr, WqT, qkvb, nullptr, qb, nullptr, BS_, 1536, 512);
  attn_k<<<dim3(S_ / 128, B_ * H_, KSPLIT), 256, 0, stream>>>(qb, qb + (long)BS_ * D_, qb + 2 * (long)BS_ * D_, Opart, Lpart);
  acomb_k<<<(BS_ * D_) / (256 * 4), 256, 0, stream>>>(Opart, Lpart, ao);
  // N=512 GEMMs: TM=32 -> 4 blocks/CU
  gemm_k<EPI_XF32, false, 32><<<dim3(4, 256), 256, 0, stream>>>(ao, nullptr, WoT, bo, x, x1, nullptr, BS_, 512, 512);

  // LN2 -> GNN (atomic-free agg; fused [nodes|agg] @ [Wgs;Wgn], K=1024)
  ln_k<<<BS_, 256, 0, stream>>>(x1, g2, be2, nx2);
  gather_k<<<BN_, 128, 0, stream>>>(nx2, nidx, rowmap, Acat);
  hipMemsetAsync(gnn, 0, (size_t)BS_ * D_ * 2, stream);
  agg_k<<<N_, 256, 0, stream>>>(ei, Acat);
  gemm_k<EPI_RELU_SCATTER, false, 32><<<dim3(4, 128), 256, 0, stream>>>(Acat, nullptr, WgsgnT, bgn, nullptr, gnn, rowmap, BN_, 512, 1024);

  // gate: K-concat GEMM [nx2 | gnn] @ WgFull^T -> gpre ; fused combine+LN3
  gemm_k<EPI_BF, true, 32><<<dim3(4, 256), 256, 0, stream>>>(nx2, gnn, WgFullT, bg, nullptr, gpre, nullptr, BS_, 512, 1024);
  combln_k<<<BS_, 256, 0, stream>>>(x1, gpre, gnn, nx2, g3, be3, x2, nx3);

  // FFN (+x2 residual) -> d_out (f32)
  gemm_k<EPI_GELU, false, 128><<<dim3(16, 64), 256, 0, stream>>>(nx3, nullptr, Wf1T, bf1, nullptr, ffh, nullptr, BS_, DFF_, 512);
  gemm_k<EPI_XF32, false, 32><<<dim3(4, 256), 256, 0, stream>>>(ffh, nullptr, Wf2T, bf2v, x2, (float*)d_out, nullptr, BS_, 512, DFF_);
}

// Round 11
// 393.328 us; speedup vs baseline: 1.0360x; 1.0360x over previous
//
#include <hip/hip_runtime.h>
#include <math.h>

using u16 = unsigned short;
using u32 = unsigned int;

typedef __attribute__((ext_vector_type(8))) short bf16x8;
typedef __attribute__((ext_vector_type(4))) float f32x4;

#define B_   4
#define S_   2048
#define D_   512
#define H_   8
#define HD_  64
#define N_   1024
#define E_   16384
#define DFF_ 2048
#define BS_  (B_ * S_)   // 8192 token rows
#define BN_  (B_ * N_)   // 4096 node rows
#define QSCALE 0.18033688011112042f   // 0.125 * log2(e): scores in log2 domain
#define KSTRIDE 68                    // 34 words ≡ 2 (mod 32) -> conflict-free col stride
#define KSPLIT 2                      // measured best (4-way worse; direct-global worse)

// ---------- bf16 helpers ----------
__device__ __forceinline__ float bf2f(u16 u) {
  u32 v = (u32)u << 16; float f; __builtin_memcpy(&f, &v, 4); return f;
}
__device__ __forceinline__ u16 f2bf(float f) {
  u32 u; __builtin_memcpy(&u, &f, 4);
  u = u + 0x7fffu + ((u >> 16) & 1u);
  return (u16)(u >> 16);
}
__device__ __forceinline__ float bflo(u32 w) {
  u32 v = w << 16; float f; __builtin_memcpy(&f, &v, 4); return f;
}
__device__ __forceinline__ float bfhi(u32 w) {
  u32 v = w & 0xffff0000u; float f; __builtin_memcpy(&f, &v, 4); return f;
}
__device__ __forceinline__ u32 fbits(float f) { u32 u; __builtin_memcpy(&u, &f, 4); return u; }

// ---------- batched weight transpose + f32->bf16 ----------
__global__ __launch_bounds__(256) void tpose_all(const float* __restrict__ Wq, const float* __restrict__ Wk,
                                                 const float* __restrict__ Wv, const float* __restrict__ Wo,
                                                 const float* __restrict__ Wgs, const float* __restrict__ Wgn,
                                                 const float* __restrict__ Wg, const float* __restrict__ Wf1,
                                                 const float* __restrict__ Wf2, u16* __restrict__ wsbase) {
  __shared__ u16 t[32][33];
  const int z = blockIdx.z;
  const float* src; int C, r0, c0, ds, co; long doff;
  const long SL = 262144;   // 512*512 u16 slot
  switch (z) {
    case 0:  src = Wq;  C = 512;  r0 = 0;   c0 = 0;    ds = 512;  co = 0;   doff = 0;       break;
    case 1:  src = Wk;  C = 512;  r0 = 0;   c0 = 0;    ds = 512;  co = 0;   doff = 1 * SL;  break;
    case 2:  src = Wv;  C = 512;  r0 = 0;   c0 = 0;    ds = 512;  co = 0;   doff = 2 * SL;  break;
    case 3:  src = Wo;  C = 512;  r0 = 0;   c0 = 0;    ds = 512;  co = 0;   doff = 3 * SL;  break;
    case 4:  src = Wg;  C = 512;  r0 = 0;   c0 = 0;    ds = 1024; co = 0;   doff = 4 * SL;  break;
    case 5:  src = Wg;  C = 512;  r0 = 512; c0 = 0;    ds = 1024; co = 512; doff = 4 * SL;  break;
    case 6:  src = Wgs; C = 512;  r0 = 0;   c0 = 0;    ds = 1024; co = 0;   doff = 6 * SL;  break;
    case 7:  src = Wgn; C = 512;  r0 = 0;   c0 = 0;    ds = 1024; co = 512; doff = 6 * SL;  break;
    case 8: case 9: case 10: case 11:
             src = Wf1; C = 2048; r0 = 0;   c0 = (z - 8) * 512;  ds = 512;  co = 0; doff = 8 * SL;  break;
    default: src = Wf2; C = 512;  r0 = (z - 12) * 512; c0 = 0;   ds = 2048; co = (z - 12) * 512; doff = 12 * SL; break;
  }
  u16* dst = wsbase + doff;
  int rb = blockIdx.x * 32, cb = blockIdx.y * 32 + c0;
  int tx = threadIdx.x, ty = threadIdx.y;
  #pragma unroll
  for (int i = ty; i < 32; i += 8) t[i][tx] = f2bf(src[(long)(r0 + rb + i) * C + cb + tx]);
  __syncthreads();
  #pragma unroll
  for (int i = ty; i < 32; i += 8) dst[(long)(cb + i) * ds + co + rb + tx] = t[tx][i];
}

// ---------- pack q/k/v biases ----------
__global__ void packb_k(const float* __restrict__ bq, const float* __restrict__ bk,
                        const float* __restrict__ bv, float* __restrict__ o) {
  int i = blockIdx.x * 256 + threadIdx.x;
  if (i < 512) o[i] = bq[i];
  else if (i < 1024) o[i] = bk[i - 512];
  else if (i < 1536) o[i] = bv[i - 1024];
}

// ---------- LayerNorm over D=512 (f32 in, bf16 out) ----------
__global__ __launch_bounds__(256) void ln_k(const float* __restrict__ x, const float* __restrict__ g,
                                            const float* __restrict__ be, u16* __restrict__ out) {
  __shared__ float red[8];
  long row = blockIdx.x;
  int t = threadIdx.x;
  const float* xr = x + row * D_;
  float2 v = *(const float2*)(xr + 2 * t);
  float s = v.x + v.y, sq = v.x * v.x + v.y * v.y;
  #pragma unroll
  for (int m = 32; m >= 1; m >>= 1) { s += __shfl_xor(s, m, 64); sq += __shfl_xor(sq, m, 64); }
  if ((t & 63) == 0) { red[t >> 6] = s; red[4 + (t >> 6)] = sq; }
  __syncthreads();
  s = red[0] + red[1] + red[2] + red[3];
  sq = red[4] + red[5] + red[6] + red[7];
  float mean = s * (1.f / D_);
  float var = sq * (1.f / D_) - mean * mean;
  float rs = rsqrtf(fmaxf(var, 0.f) + 1e-5f);
  float2 gw = *(const float2*)(g + 2 * t);
  float2 bw = *(const float2*)(be + 2 * t);
  u32 o = (u32)f2bf((v.x - mean) * rs * gw.x + bw.x) | ((u32)f2bf((v.y - mean) * rs * gw.y + bw.y) << 16);
  *(u32*)&out[row * D_ + 2 * t] = o;
}

// ---------- MFMA GEMM (BK=64 batch-staged, XCD-swizzled block ids), fused epilogues ----------
// MEASURED OPTIMUM across r8 (BK=32 dbuf: -10us) and r10 (3-ring counted-vmcnt + T2
// swizzle: -5us): BK=64 batch-stage (issue 8 loads -> drain -> 2x compute). The batched
// drains are covered by co-resident blocks at these small-K shapes (m99/m100-consistent).
// TM=128: wide-N GEMMs. TM=32: N=512 GEMMs (grid otherwise 1-2 blocks/CU).
__device__ __forceinline__ void async_cp16(const u16* g, u16* l) {
  __builtin_amdgcn_global_load_lds((const __attribute__((address_space(1))) void*)g,
                                   (__attribute__((address_space(3))) void*)l, 16, 0, 0);
}

enum { EPI_QKV3, EPI_XF32, EPI_BF, EPI_RELU_SCATTER, EPI_GELU };

template <int EPI, bool CAT = false, int TM = 128>
__global__ __launch_bounds__(256) void gemm_k(const u16* __restrict__ A, const u16* __restrict__ A2,
                                              const u16* __restrict__ Bt, const float* __restrict__ bias,
                                              const void* src, void* out, const int* __restrict__ rowmap,
                                              int M, int N, int K) {
  constexpr int MT = (TM >= 32) ? (TM / 32) : 1;   // m-subtiles per wave
  __shared__ __align__(16) u16 As[2 * TM * 32];   // two 32-K slabs
  __shared__ __align__(16) u16 Bs[8192];          // 2 x (128 x 32)
  int tid = threadIdx.x;
  int lane = tid & 63;
  int wn = (tid >> 6) & 1;
  int wm = (tid >> 7) & 1;
  // T1 XCD swizzle (all launches have nwg % 8 == 0): contiguous wgid chunk per XCD ->
  // same-A-panel blocks land on one XCD's L2.
  int nwg = gridDim.x * gridDim.y;
  int orig = blockIdx.y * gridDim.x + blockIdx.x;
  int wgid = ((orig & 7) * (nwg >> 3)) + (orig >> 3);
  int bx = wgid % gridDim.x;
  int by = wgid / gridDim.x;
  long m0 = (long)by * TM;
  long n0 = (long)bx * 128;

  f32x4 acc[MT][4];
  {
    f32x4 z = {0.f, 0.f, 0.f, 0.f};
    #pragma unroll
    for (int i = 0; i < MT; i++)
      #pragma unroll
      for (int j = 0; j < 4; j++) acc[i][j] = z;
  }

  int srow = tid >> 2;           // 0..63
  int skoff = (tid & 3) * 8;
  const int astride = CAT ? 512 : K;
  const u16* Ag  = A + (m0 + srow) * (long)astride + skoff;
  const u16* A2g = CAT ? (A2 + (m0 + srow) * (long)astride + skoff) : nullptr;
  const u16* Bg  = Bt + (n0 + srow) * (long)K + skoff;
  int rsel = lane & 15;
  int kchunk = (lane >> 4) * 8;

  for (int kt = 0; kt < K; kt += 64) {
    __syncthreads();
    #pragma unroll
    for (int s = 0; s < 2; s++) {
      int kts = kt + s * 32;
      const u16* Asrc = (CAT && kts >= 512) ? (A2g + (kts - 512)) : (Ag + kts);
      if constexpr (TM == 32) {
        // A slab = 32 rows x 32 k = 1024 u16: staged by waves 0-1 only (srow 0..31),
        // wave-uniform guard, lane-linear LDS dest (global_load_lds requirement).
        if (tid < 128) async_cp16(Asrc, As + s * (TM * 32) + tid * 8);
      } else {
        async_cp16(Asrc, As + s * (TM * 32) + tid * 8);
        if constexpr (TM == 128) async_cp16(Asrc + (long)64 * astride, As + s * (TM * 32) + 2048 + tid * 8);
      }
      async_cp16(Bg + kts, Bs + s * 4096 + tid * 8);
      async_cp16(Bg + (long)64 * K + kts, Bs + s * 4096 + 2048 + tid * 8);
    }
    __syncthreads();
    #pragma unroll
    for (int s = 0; s < 2; s++) {
      bf16x8 af[MT], bfv[4];
      #pragma unroll
      for (int mt = 0; mt < MT; mt++)
        af[mt] = *(const bf16x8*)&As[s * (TM * 32) + (wm * (TM / 2) + mt * 16 + rsel) * 32 + kchunk];
      #pragma unroll
      for (int nt = 0; nt < 4; nt++)
        bfv[nt] = *(const bf16x8*)&Bs[s * 4096 + (wn * 64 + nt * 16 + rsel) * 32 + kchunk];
      #pragma unroll
      for (int mt = 0; mt < MT; mt++)
        #pragma unroll
        for (int nt = 0; nt < 4; nt++)
          acc[mt][nt] = __builtin_amdgcn_mfma_f32_16x16x32_bf16(af[mt], bfv[nt], acc[mt][nt], 0, 0, 0);
    }
  }

  int rbase = (lane >> 4) * 4;   // C layout: row = quad*4 + reg, col = lane&15 (m89-verified)
  int cbase = lane & 15;
  #pragma unroll
  for (int mt = 0; mt < MT; mt++) {
    #pragma unroll
    for (int nt = 0; nt < 4; nt++) {
      long col = n0 + wn * 64 + nt * 16 + cbase;
      float bv = bias ? bias[col] : 0.f;
      long row0 = m0 + wm * (TM / 2) + mt * 16 + rbase;
      float vals[4];
      #pragma unroll
      for (int r = 0; r < 4; r++) vals[r] = acc[mt][nt][r] + bv;
      if constexpr (EPI == EPI_QKV3) {
        long which = col >> 9;            // 0=q, 1=k, 2=v
        long cc = col & 511;
        long b = row0 >> 11;
        long h = cc >> 6, d = cc & 63;
        if (which == 2) {                 // V transposed [b,h,d,key]; 4 consecutive keys
          long sI0 = row0 & 2047;
          uint2 w;
          w.x = (u32)f2bf(vals[0]) | ((u32)f2bf(vals[1]) << 16);
          w.y = (u32)f2bf(vals[2]) | ((u32)f2bf(vals[3]) << 16);
          *(uint2*)&((u16*)out)[2 * (long)BS_ * D_ + (((b * H_ + h) * HD_) + d) * S_ + sI0] = w;
        } else {
          #pragma unroll
          for (int r = 0; r < 4; r++) {
            long sI = (row0 + r) & 2047;
            float v2 = (which == 0) ? vals[r] * QSCALE : vals[r];
            ((u16*)out)[which * (long)BS_ * D_ + (((b * H_ + h) * S_) + sI) * HD_ + d] = f2bf(v2);
          }
        }
      } else {
        #pragma unroll
        for (int r = 0; r < 4; r++) {
          long row = row0 + r;
          float val = vals[r];
          if constexpr (EPI == EPI_XF32) {
            ((float*)out)[row * N + col] = val + ((const float*)src)[row * N + col];
          } else if constexpr (EPI == EPI_BF) {
            ((u16*)out)[row * N + col] = f2bf(val);
          } else if constexpr (EPI == EPI_RELU_SCATTER) {
            long orow = rowmap[row];
            ((u16*)out)[orow * D_ + col] = f2bf(fmaxf(val, 0.f));
          } else if constexpr (EPI == EPI_GELU) {
            ((u16*)out)[row * N + col] = f2bf(0.5f * val * (1.f + erff(val * 0.70710678118654752f)));
          }
        }
      }
    }
  }
}

// ---------- MFMA flash attention, S^T scheme, 2 q-tiles/wave, 2-way K-split ----------
// MEASURED OPTIMUM — byte-identical to r6/r9. Single-buffered LDS, NO setprio, NO
// prefetch: sits exactly on the 64-VGPR wave-residency cliff (m69); r7 (prefetch,
// VGPR 76) and r8 (setprio, VGPR 68) both crossed it -> occupancy 32->21, +10us.
__global__ __launch_bounds__(256) void attn_k(const u16* __restrict__ Q, const u16* __restrict__ Kv,
                                              const u16* __restrict__ VT, u16* __restrict__ Opart,
                                              float* __restrict__ Lp) {
  __shared__ __align__(16) u16 Ks[64 * KSTRIDE];
  __shared__ __align__(16) u16 Vs[64 * KSTRIDE];
  int tid = threadIdx.x;
  int lane = tid & 63;
  int wave = tid >> 6;
  int col = lane & 15;
  int quad = lane >> 4;
  int bh = blockIdx.y;
  int q0 = blockIdx.x * 128;
  int khalf = blockIdx.z;
  long base = (long)bh * S_;
  long vbase = (long)bh * HD_ * S_;

  const u16* qpa = Q + (base + q0 + wave * 32 + col) * HD_;
  const u16* qpb = qpa + 16 * HD_;
  bf16x8 bqa0 = *(const bf16x8*)(qpa + quad * 8);
  bf16x8 bqa1 = *(const bf16x8*)(qpa + 32 + quad * 8);
  bf16x8 bqb0 = *(const bf16x8*)(qpb + quad * 8);
  bf16x8 bqb1 = *(const bf16x8*)(qpb + 32 + quad * 8);

  float la = 0.f, lb = 0.f;
  f32x4 accA[4], accB[4];
  {
    f32x4 z = {0.f, 0.f, 0.f, 0.f};
    #pragma unroll
    for (int mt = 0; mt < 4; mt++) { accA[mt] = z; accB[mt] = z; }
  }

  int srow = tid >> 2;
  int sdc = (tid & 3) * 16;
  const bool hiQ = (quad >= 2);
  const int s0 = (quad & 1) * 2;
  const int a0 = (s0 * 16 + col + wave * 64) * 4;
  const int a1 = ((s0 + 1) * 16 + col + wave * 64) * 4;

  int kt0 = khalf * (S_ / KSPLIT);
  for (int kt = kt0; kt < kt0 + S_ / KSPLIT; kt += 64) {
    __syncthreads();
    {
      const u16* kg = Kv + (base + kt + srow) * HD_ + sdc;
      *(bf16x8*)&Ks[srow * KSTRIDE + sdc]     = *(const bf16x8*)kg;
      *(bf16x8*)&Ks[srow * KSTRIDE + sdc + 8] = *(const bf16x8*)(kg + 8);
      const u16* vg = VT + (vbase + (long)srow * S_) + kt + sdc;
      *(bf16x8*)&Vs[srow * KSTRIDE + sdc]     = *(const bf16x8*)vg;
      *(bf16x8*)&Vs[srow * KSTRIDE + sdc + 8] = *(const bf16x8*)(vg + 8);
    }
    __syncthreads();

    f32x4 sa[4], sb[4];
    #pragma unroll
    for (int nt = 0; nt < 4; nt++) {
      bf16x8 ak0 = *(const bf16x8*)&Ks[(nt * 16 + col) * KSTRIDE + quad * 8];
      bf16x8 ak1 = *(const bf16x8*)&Ks[(nt * 16 + col) * KSTRIDE + 32 + quad * 8];
      f32x4 z = {0.f, 0.f, 0.f, 0.f};
      z = __builtin_amdgcn_mfma_f32_16x16x32_bf16(ak0, bqa0, z, 0, 0, 0);
      z = __builtin_amdgcn_mfma_f32_16x16x32_bf16(ak1, bqa1, z, 0, 0, 0);
      sa[nt] = z;
      f32x4 y = {0.f, 0.f, 0.f, 0.f};
      y = __builtin_amdgcn_mfma_f32_16x16x32_bf16(ak0, bqb0, y, 0, 0, 0);
      y = __builtin_amdgcn_mfma_f32_16x16x32_bf16(ak1, bqb1, y, 0, 0, 0);
      sb[nt] = y;
    }

    u32 pka[4][2], pkb[4][2];
    #pragma unroll
    for (int nt = 0; nt < 4; nt++) {
      #pragma unroll
      for (int r = 0; r < 4; r++) { sa[nt][r] = __builtin_amdgcn_exp2f(sa[nt][r]); sb[nt][r] = __builtin_amdgcn_exp2f(sb[nt][r]); }
      la += (sa[nt][0] + sa[nt][1]) + (sa[nt][2] + sa[nt][3]);
      lb += (sb[nt][0] + sb[nt][1]) + (sb[nt][2] + sb[nt][3]);
      pka[nt][0] = __builtin_amdgcn_perm(fbits(sa[nt][1]), fbits(sa[nt][0]), 0x07060302u);
      pka[nt][1] = __builtin_amdgcn_perm(fbits(sa[nt][3]), fbits(sa[nt][2]), 0x07060302u);
      pkb[nt][0] = __builtin_amdgcn_perm(fbits(sb[nt][1]), fbits(sb[nt][0]), 0x07060302u);
      pkb[nt][1] = __builtin_amdgcn_perm(fbits(sb[nt][3]), fbits(sb[nt][2]), 0x07060302u);
    }

    union { u32 d[4]; bf16x8 v; } ba0, ba1, bb0, bb1;
    {
      u32 sA = hiQ ? pka[1][0] : pka[0][0];
      u32 sB = hiQ ? pka[1][1] : pka[0][1];
      ba0.d[0] = __builtin_amdgcn_ds_bpermute(a0, sA);
      ba0.d[1] = __builtin_amdgcn_ds_bpermute(a0, sB);
      ba0.d[2] = __builtin_amdgcn_ds_bpermute(a1, sA);
      ba0.d[3] = __builtin_amdgcn_ds_bpermute(a1, sB);
      u32 sC = hiQ ? pka[3][0] : pka[2][0];
      u32 sD = hiQ ? pka[3][1] : pka[2][1];
      ba1.d[0] = __builtin_amdgcn_ds_bpermute(a0, sC);
      ba1.d[1] = __builtin_amdgcn_ds_bpermute(a0, sD);
      ba1.d[2] = __builtin_amdgcn_ds_bpermute(a1, sC);
      ba1.d[3] = __builtin_amdgcn_ds_bpermute(a1, sD);
      u32 tA = hiQ ? pkb[1][0] : pkb[0][0];
      u32 tB = hiQ ? pkb[1][1] : pkb[0][1];
      bb0.d[0] = __builtin_amdgcn_ds_bpermute(a0, tA);
      bb0.d[1] = __builtin_amdgcn_ds_bpermute(a0, tB);
      bb0.d[2] = __builtin_amdgcn_ds_bpermute(a1, tA);
      bb0.d[3] = __builtin_amdgcn_ds_bpermute(a1, tB);
      u32 tC = hiQ ? pkb[3][0] : pkb[2][0];
      u32 tD = hiQ ? pkb[3][1] : pkb[2][1];
      bb1.d[0] = __builtin_amdgcn_ds_bpermute(a0, tC);
      bb1.d[1] = __builtin_amdgcn_ds_bpermute(a0, tD);
      bb1.d[2] = __builtin_amdgcn_ds_bpermute(a1, tC);
      bb1.d[3] = __builtin_amdgcn_ds_bpermute(a1, tD);
    }

    #pragma unroll
    for (int mt = 0; mt < 4; mt++) {
      bf16x8 av0 = *(const bf16x8*)&Vs[(mt * 16 + col) * KSTRIDE + quad * 8];
      bf16x8 av1 = *(const bf16x8*)&Vs[(mt * 16 + col) * KSTRIDE + 32 + quad * 8];
      accA[mt] = __builtin_amdgcn_mfma_f32_16x16x32_bf16(av0, ba0.v, accA[mt], 0, 0, 0);
      accA[mt] = __builtin_amdgcn_mfma_f32_16x16x32_bf16(av1, ba1.v, accA[mt], 0, 0, 0);
      accB[mt] = __builtin_amdgcn_mfma_f32_16x16x32_bf16(av0, bb0.v, accB[mt], 0, 0, 0);
      accB[mt] = __builtin_amdgcn_mfma_f32_16x16x32_bf16(av1, bb1.v, accB[mt], 0, 0, 0);
    }
  }

  la += __shfl_xor(la, 16, 64);
  la += __shfl_xor(la, 32, 64);
  lb += __shfl_xor(lb, 16, 64);
  lb += __shfl_xor(lb, 32, 64);

  int b = bh >> 3, h = bh & 7;
  long qrowA = (long)(b * S_) + q0 + wave * 32 + col;
  u16* Pp = Opart + (long)khalf * BS_ * D_;
  if (quad == 0) {
    float* lr = Lp + ((long)(khalf * 32 + bh)) * S_ + q0 + wave * 32;
    lr[col] = la;
    lr[16 + col] = lb;
  }
  u16* opA = Pp + qrowA * D_ + h * HD_ + quad * 4;
  u16* opB = Pp + (qrowA + 16) * D_ + h * HD_ + quad * 4;
  #pragma unroll
  for (int mt = 0; mt < 4; mt++) {
    uint2 w;
    w.x = (u32)f2bf(accA[mt][0]) | ((u32)f2bf(accA[mt][1]) << 16);
    w.y = (u32)f2bf(accA[mt][2]) | ((u32)f2bf(accA[mt][3]) << 16);
    *(uint2*)(opA + mt * 16) = w;
    uint2 v;
    v.x = (u32)f2bf(accB[mt][0]) | ((u32)f2bf(accB[mt][1]) << 16);
    v.y = (u32)f2bf(accB[mt][2]) | ((u32)f2bf(accB[mt][3]) << 16);
    *(uint2*)(opB + mt * 16) = v;
  }
}

// ---------- combine K-split partials: ao = sum(Pk) / sum(lk) ----------
__global__ __launch_bounds__(256) void acomb_k(const u16* __restrict__ P, const float* __restrict__ Lp,
                                               u16* __restrict__ AO) {
  long i = (long)blockIdx.x * 256 + threadIdx.x;   // uint2 = 4 bf16 elems
  long e0 = i * 4;
  long tok = e0 >> 9;             // /512
  int hh = (int)((e0 >> 6) & 7);
  long s = tok & 2047;
  long bb = tok >> 11;
  long bh = bb * 8 + hh;
  float l = 0.f;
  float v0 = 0.f, v1 = 0.f, v2 = 0.f, v3 = 0.f;
  #pragma unroll
  for (int k = 0; k < KSPLIT; k++) {
    uint2 a = ((const uint2*)(P + (long)k * BS_ * D_))[i];
    v0 += bflo(a.x); v1 += bfhi(a.x);
    v2 += bflo(a.y); v3 += bfhi(a.y);
    l += Lp[((long)(k * 32) + bh) * S_ + s];
  }
  float inv = 1.f / l;
  uint2 o;
  o.x = (u32)f2bf(v0 * inv) | ((u32)f2bf(v1 * inv) << 16);
  o.y = (u32)f2bf(v2 * inv) | ((u32)f2bf(v3 * inv) << 16);
  ((uint2*)AO)[i] = o;
}

// ---------- GNN plumbing ----------
// gather nx2 node rows into Acat cols 0..511; also emits rowmap for the scatter epilogue
__global__ __launch_bounds__(128) void gather_k(const u16* __restrict__ nx2, const int* __restrict__ nidx,
                                                int* __restrict__ rowmap, u16* __restrict__ Acat) {
  int bn = blockIdx.x;
  int t = threadIdx.x;
  long srow = (long)(bn >> 10) * S_ + nidx[bn];
  if (t == 0) rowmap[bn] = (int)srow;
  const u32* sp = (const u32*)(nx2 + srow * D_);
  u32* dp = (u32*)(Acat + (long)bn * 1024);
  dp[t] = sp[t];
  dp[t + 128] = sp[t + 128];
}

// ---------- atomic-free segment sum: one block per dst node ----------
#define DEG_CAP 256
__global__ __launch_bounds__(256) void agg_k(const int* __restrict__ ei, u16* __restrict__ Acat) {
  __shared__ int cnt;
  __shared__ int lst[DEG_CAP];
  int n = blockIdx.x;
  int t = threadIdx.x;
  if (t == 0) cnt = 0;
  __syncthreads();
  const int* dst = ei + E_;
  for (int e = t; e < E_; e += 256) {
    if (dst[e] == n) {
      int idx = atomicAdd(&cnt, 1);
      if (idx < DEG_CAP) lst[idx] = ei[e];
    }
  }
  __syncthreads();
  int mcnt = cnt < DEG_CAP ? cnt : DEG_CAP;
  float2 acc[4] = {{0.f, 0.f}, {0.f, 0.f}, {0.f, 0.f}, {0.f, 0.f}};
  for (int i = 0; i < mcnt; i++) {
    long s = lst[i];
    #pragma unroll
    for (int b = 0; b < 4; b++) {
      u32 w = *(const u32*)&Acat[((long)(b * N_) + s) * 1024 + 2 * t];
      acc[b].x += bflo(w);
      acc[b].y += bfhi(w);
    }
  }
  #pragma unroll
  for (int b = 0; b < 4; b++) {
    u32 r = (u32)f2bf(acc[b].x) | ((u32)f2bf(acc[b].y) << 16);
    *(u32*)&Acat[((long)(b * N_) + n) * 1024 + 512 + 2 * t] = r;
  }
}

// ---------- fused gated combine + LN3 ----------
__global__ __launch_bounds__(256) void combln_k(const float* __restrict__ x1, const u16* __restrict__ gpre,
                                                const u16* __restrict__ gnn, const u16* __restrict__ nx2,
                                                const float* __restrict__ g3, const float* __restrict__ be3,
                                                float* __restrict__ x2, u16* __restrict__ nx3) {
  __shared__ float red[8];
  long row = blockIdx.x;
  int t = threadIdx.x;
  long off = row * D_ + 2 * t;
  float2 a = *(const float2*)(x1 + off);
  u32 gp = *(const u32*)(gpre + off);
  u32 gn = *(const u32*)(gnn + off);
  u32 nv = *(const u32*)(nx2 + off);
  float g0 = 1.f / (1.f + __expf(-bflo(gp)));
  float g1 = 1.f / (1.f + __expf(-bfhi(gp)));
  float t0 = a.x + g0 * bflo(gn) + (1.f - g0) * bflo(nv);
  float t1 = a.y + g1 * bfhi(gn) + (1.f - g1) * bfhi(nv);
  float2 w = {t0, t1};
  *(float2*)(x2 + off) = w;
  float s = t0 + t1, sq = t0 * t0 + t1 * t1;
  #pragma unroll
  for (int m = 32; m >= 1; m >>= 1) { s += __shfl_xor(s, m, 64); sq += __shfl_xor(sq, m, 64); }
  if ((t & 63) == 0) { red[t >> 6] = s; red[4 + (t >> 6)] = sq; }
  __syncthreads();
  s = red[0] + red[1] + red[2] + red[3];
  sq = red[4] + red[5] + red[6] + red[7];
  float mean = s * (1.f / D_);
  float var = sq * (1.f / D_) - mean * mean;
  float rs = rsqrtf(fmaxf(var, 0.f) + 1e-5f);
  float2 gw = *(const float2*)(g3 + 2 * t);
  float2 bw = *(const float2*)(be3 + 2 * t);
  u32 o = (u32)f2bf((t0 - mean) * rs * gw.x + bw.x) | ((u32)f2bf((t1 - mean) * rs * gw.y + bw.y) << 16);
  *(u32*)&nx3[off] = o;
}

// ---------- orchestration ----------
extern "C" void kernel_launch(void* const* d_in, const int* in_sizes, int n_in,
                              void* d_out, int out_size, void* d_ws, size_t ws_size,
                              hipStream_t stream) {
  const float* x  = (const float*)d_in[0];
  const int* ei   = (const int*)d_in[1];
  const int* nidx = (const int*)d_in[2];
  const float* Wq = (const float*)d_in[3];   const float* bq = (const float*)d_in[4];
  const float* Wk = (const float*)d_in[5];   const float* bk = (const float*)d_in[6];
  const float* Wv = (const float*)d_in[7];   const float* bv = (const float*)d_in[8];
  const float* Wo = (const float*)d_in[9];   const float* bo = (const float*)d_in[10];
  const float* Wf1 = (const float*)d_in[11]; const float* bf1 = (const float*)d_in[12];
  const float* Wf2 = (const float*)d_in[13]; const float* bf2v = (const float*)d_in[14];
  const float* g1 = (const float*)d_in[15];  const float* be1 = (const float*)d_in[16];
  const float* g2 = (const float*)d_in[17];  const float* be2 = (const float*)d_in[18];
  const float* g3 = (const float*)d_in[19];  const float* be3 = (const float*)d_in[20];
  const float* Wg = (const float*)d_in[21];  const float* bg = (const float*)d_in[22];
  const float* Wgs = (const float*)d_in[23]; const float* Wgn = (const float*)d_in[24];
  const float* bgn = (const float*)d_in[25];

  const size_t MB8 = (size_t)8 * 1024 * 1024;
  char* base = (char*)d_ws;
  const size_t SLOT = (size_t)512 * 512 * 2;   // 512 KB
  u16* WqT     = (u16*)(base + 0 * SLOT);
  u16* WoT     = (u16*)(base + 3 * SLOT);
  u16* WgFullT = (u16*)(base + 4 * SLOT);
  u16* WgsgnT  = (u16*)(base + 6 * SLOT);
  u16* Wf1T    = (u16*)(base + 8 * SLOT);
  u16* Wf2T    = (u16*)(base + 12 * SLOT);

  char* RA   = base + 16 * SLOT;   // 8M: nx -> ao -> gnn -> nx3
  char* Rqb  = RA + MB8;           // 8M
  char* Rkb  = Rqb + MB8;          // 8M
  char* Rvb  = Rkb + MB8;          // 8M
  char* Rac  = Rvb + MB8;          // 8M: Opart[0] -> Acat -> gpre
  char* Rag  = Rac + MB8;          // 8M: Opart[1]
  char* Rx2  = Rag + MB8;          // 16M: x2 (f32)
  char* RM   = Rx2 + 2 * MB8;      // rowmap 16KB + qkvb 6KB + Lpart 512KB

  u16* nx   = (u16*)RA;   u16* ao  = (u16*)RA;   u16* gnn = (u16*)RA;  u16* nx3 = (u16*)RA;
  u16* qb   = (u16*)Rqb;           // q | k | v^T contiguous (EPI_QKV3 offsets)
  float* x1 = (float*)Rqb;
  u16* nx2  = (u16*)Rvb;
  u16* Opart = (u16*)Rac;          // KSPLIT x 8MB contiguous (Rac,Rag); dead before Acat/gpre
  u16* Acat = (u16*)Rac;
  u16* gpre = (u16*)Rac;
  float* x2 = (float*)Rx2;
  u16* ffh  = (u16*)Rqb;
  int* rowmap = (int*)RM;
  float* qkvb = (float*)(RM + 16384);
  float* Lpart = (float*)(RM + 32768);   // KSPLIT*32*2048 f32 = 512KB

  dim3 tb(32, 8);
  tpose_all<<<dim3(16, 16, 16), tb, 0, stream>>>(Wq, Wk, Wv, Wo, Wgs, Wgn, Wg, Wf1, Wf2, (u16*)base);
  packb_k<<<6, 256, 0, stream>>>(bq, bk, bv, qkvb);

  // LN1 -> fused QKV (Q scaled, V transposed) -> K-split attention -> combine -> O-proj (+x residual)
  ln_k<<<BS_, 256, 0, stream>>>(x, g1, be1, nx);
  gemm_k<EPI_QKV3, false, 128><<<dim3(12, 64), 256, 0, stream>>>(nx, nullptr, WqT, qkvb, nullptr, qb, nullptr, BS_, 1536, 512);
  attn_k<<<dim3(S_ / 128, B_ * H_, KSPLIT), 256, 0, stream>>>(qb, qb + (long)BS_ * D_, qb + 2 * (long)BS_ * D_, Opart, Lpart);
  acomb_k<<<(BS_ * D_) / (256 * 4), 256, 0, stream>>>(Opart, Lpart, ao);
  // N=512 GEMMs: TM=32 -> 4 blocks/CU
  gemm_k<EPI_XF32, false, 32><<<dim3(4, 256), 256, 0, stream>>>(ao, nullptr, WoT, bo, x, x1, nullptr, BS_, 512, 512);

  // LN2 -> GNN (atomic-free agg; fused [nodes|agg] @ [Wgs;Wgn], K=1024)
  ln_k<<<BS_, 256, 0, stream>>>(x1, g2, be2, nx2);
  gather_k<<<BN_, 128, 0, stream>>>(nx2, nidx, rowmap, Acat);
  hipMemsetAsync(gnn, 0, (size_t)BS_ * D_ * 2, stream);
  agg_k<<<N_, 256, 0, stream>>>(ei, Acat);
  gemm_k<EPI_RELU_SCATTER, false, 32><<<dim3(4, 128), 256, 0, stream>>>(Acat, nullptr, WgsgnT, bgn, nullptr, gnn, rowmap, BN_, 512, 1024);

  // gate: K-concat GEMM [nx2 | gnn] @ WgFull^T -> gpre ; fused combine+LN3
  gemm_k<EPI_BF, true, 32><<<dim3(4, 256), 256, 0, stream>>>(nx2, gnn, WgFullT, bg, nullptr, gpre, nullptr, BS_, 512, 1024);
  combln_k<<<BS_, 256, 0, stream>>>(x1, gpre, gnn, nx2, g3, be3, x2, nx3);

  // FFN (+x2 residual) -> d_out (f32)
  gemm_k<EPI_GELU, false, 128><<<dim3(16, 64), 256, 0, stream>>>(nx3, nullptr, Wf1T, bf1, nullptr, ffh, nullptr, BS_, DFF_, 512);
  gemm_k<EPI_XF32, false, 32><<<dim3(4, 256), 256, 0, stream>>>(ffh, nullptr, Wf2T, bf2v, x2, (float*)d_out, nullptr, BS_, 512, DFF_);
}